// Round 1
// baseline (352.485 us; speedup 1.0000x reference)
//
#include <hip/hip_runtime.h>
#include <hip/hip_bf16.h>

// AngularMarginLoss: B=2048, D=256, C=100000
// loss = -mean_b( num_b - log(exp(num_b) + sum_{c!=t_b} exp(30*cos_bc) + 1e-6) )
// num_b = 30*cos(acos(clip(cos_bt)) + 0.2)
//
// Round-9: occupancy + serial-tail attack.
//  * k_main was latency-bound: 1564 one-wave blocks = ~1.5 waves/SIMD, so the
//    per-tile serial tail (MFMA-dep wait -> 16 mul -> 16 v_exp -> reduce) left
//    the matrix pipe idle ~70% (MfmaUtil 29 == %-of-peak 27.6).
//  * SSPLIT=4 sample-split -> 6256 waves ~= 3 fill rounds of the 2048 resident
//    slots (224-reg footprint -> 2 waves/SIMD cap). XCD-grouping swizzle puts
//    the 4 siblings of a slice on one XCD so W streams ~once per XCD group.
//  * embF pre-scaled by 30*log2(e): MFMA emits d = 30*log2e*cos, exp(30*cos)
//    becomes a single v_exp_f32 (exp2) -- removes the dependent v_mul chain.
//  * partial[1564][2048] (12.5MB W + 12.8MB R + heavy k_finish) replaced by
//    8KB atomicAdd accumulator (<=1564 atomics/address over ~25us: free).

static constexpr int Bn = 2048;
static constexpr int Dn = 256;
static constexpr int Cn = 100000;
static constexpr int NSLICE = 1564;                 // 64-col wave slices
static constexpr int SSPLIT = 4;                    // sample-dim split per slice
static constexpr int CPAD   = NSLICE * 64;          // 100096
static constexpr float OOB_COLS = (float)(CPAD - Cn);   // 96 (exp2(0)=1 each)
static constexpr int NT  = Bn / 16;                 // 128 sample tiles
static constexpr int NTW = NT / SSPLIT;             // 32 tiles per wave

#define SCALE_F 30.0f
#define MARGIN_F 0.2f
#define EPS_F 1e-6f
#define L2E_SCALE 43.2808512266689f   /* 30 * log2(e): exp(30*c) = 2^(L2E*c) */

typedef __attribute__((ext_vector_type(8))) short bf16x8;   // 8 bf16 = 4 VGPRs
typedef __attribute__((ext_vector_type(4))) float f32x4;

__device__ __forceinline__ short f2bf_rne(float x) {
    union { float f; unsigned int u; } v; v.f = x;
    unsigned int r = v.u + 0x7fffu + ((v.u >> 16) & 1u);
    return (short)(r >> 16);
}

// ---- kernel 1: fused prep ----
// blocks [0,256)    : pack emb fp32 -> embF (bf16, MFMA B-fragment order),
//                     PRE-SCALED by 30*log2(e) so k_main's exp is a bare v_exp.
//   chunk (t,ks,lane): embF[((t*8+ks)*64+lane)*8 .. +7] = bf16 of
//   L2E * emb[t*16 + (lane&15)][ks*32 + (lane>>4)*8 + j], j=0..7
// blocks [256,768)  : per-sample target cosine -> numv, etv (exact fp32 path)
__global__ __launch_bounds__(256) void k_prep(const float* __restrict__ W,
                                              const float* __restrict__ emb,
                                              const int* __restrict__ tgt,
                                              short* __restrict__ embF,
                                              float* __restrict__ numv,
                                              float* __restrict__ etv) {
    const int blk = blockIdx.x;
    if (blk < 256) {
        const int t     = blk >> 1;
        const int chunk = (blk & 1) * 256 + threadIdx.x;   // [0,512)
        const int ks    = chunk >> 6;
        const int lane  = chunk & 63;
        const int q     = lane >> 4;
        const int cr    = lane & 15;
        const float* src = emb + (size_t)(t * 16 + cr) * Dn + ks * 32 + q * 8;
        float4 x0 = *(const float4*)(src);
        float4 x1 = *(const float4*)(src + 4);
        bf16x8 o;
        o[0] = f2bf_rne(x0.x * L2E_SCALE); o[1] = f2bf_rne(x0.y * L2E_SCALE);
        o[2] = f2bf_rne(x0.z * L2E_SCALE); o[3] = f2bf_rne(x0.w * L2E_SCALE);
        o[4] = f2bf_rne(x1.x * L2E_SCALE); o[5] = f2bf_rne(x1.y * L2E_SCALE);
        o[6] = f2bf_rne(x1.z * L2E_SCALE); o[7] = f2bf_rne(x1.w * L2E_SCALE);
        *(bf16x8*)(embF + (size_t)((t * 8 + ks) * 64 + lane) * 8) = o;
    } else {
        const int b    = (blk - 256) * 4 + (threadIdx.x >> 6);
        const int lane = threadIdx.x & 63;
        const int t    = tgt[b];
        float4 x = *(const float4*)(W + (size_t)t * Dn + lane * 4);
        float4 e = *(const float4*)(emb + b * Dn + lane * 4);
        float dot = x.x * e.x + x.y * e.y + x.z * e.z + x.w * e.w;
        float ss  = x.x * x.x + x.y * x.y + x.z * x.z + x.w * x.w;
#pragma unroll
        for (int o = 1; o < 64; o <<= 1) {
            dot += __shfl_xor(dot, o);
            ss  += __shfl_xor(ss, o);
        }
        if (lane == 0) {
            float cosv = dot / fmaxf(sqrtf(ss), 1e-12f);
            cosv = fminf(fmaxf(cosv, -1.f), 1.f);
            const float num = SCALE_F * cosf(acosf(cosv) + MARGIN_F);
            numv[b] = num;
            etv[b]  = __expf(SCALE_F * cosv);
        }
    }
}

// ---- kernel 2: main fused GEMM + exp row-sum (1 wave/block, no LDS) ----
// Block (sl, h): 64 cols of slice sl x 512 samples (tiles [h*32, h*32+32)).
__global__ __launch_bounds__(64, 2) void k_main(const float* __restrict__ W,
                                                const short* __restrict__ embF,
                                                float* __restrict__ acc) {
    const int lane = threadIdx.x;
    const int q    = lane >> 4;   // quad 0..3
    const int cr   = lane & 15;

    // XCD-grouping swizzle: blockIdx round-robins XCDs (bx&7). Map so the 4
    // sibling waves of one slice (same W rows) are consecutive work items on
    // ONE XCD and dispatched within 32 blocks of each other -> W L2-shared.
    const int grp = (NSLICE * SSPLIT) >> 3;            // 782, exact (6256%8==0)
    const int w   = (blockIdx.x & 7) * grp + (blockIdx.x >> 3);
    const int sl  = w >> 2;                            // SSPLIT == 4
    const int h   = w & 3;
    const int cbase = sl * 64;
    const int t0    = h * NTW;

    // ---- prologue: 2-pass normalize from fp32 W (pass 2 cache-hot) ----
    // A layout (16x16x32): lane holds A[m=cr][k=q*8+j] per 32-wide k-step.
    bf16x8 afrag[4][8];
#pragma unroll
    for (int ct = 0; ct < 4; ++ct) {
        const int c = cbase + ct * 16 + cr;
        const float* wr = W + (size_t)c * Dn;
        float ss = 0.0f;
        if (c < Cn) {
#pragma unroll
            for (int ks = 0; ks < 8; ++ks) {
                float4 x0 = *(const float4*)(wr + ks * 32 + q * 8);
                float4 x1 = *(const float4*)(wr + ks * 32 + q * 8 + 4);
                ss += x0.x * x0.x + x0.y * x0.y + x0.z * x0.z + x0.w * x0.w;
                ss += x1.x * x1.x + x1.y * x1.y + x1.z * x1.z + x1.w * x1.w;
            }
        }
        // lanes {cr, cr+16, cr+32, cr+48} hold 64 distinct elements of row c
        ss += __shfl_xor(ss, 16);
        ss += __shfl_xor(ss, 32);
        const float rn = 1.0f / fmaxf(sqrtf(ss), 1e-12f);
#pragma unroll
        for (int ks = 0; ks < 8; ++ks) {
            bf16x8 a = {0, 0, 0, 0, 0, 0, 0, 0};
            if (c < Cn) {   // pass 2: reload (cache-hot), scale, convert
                float4 x0 = *(const float4*)(wr + ks * 32 + q * 8);
                float4 x1 = *(const float4*)(wr + ks * 32 + q * 8 + 4);
                a[0] = f2bf_rne(x0.x * rn); a[1] = f2bf_rne(x0.y * rn);
                a[2] = f2bf_rne(x0.z * rn); a[3] = f2bf_rne(x0.w * rn);
                a[4] = f2bf_rne(x1.x * rn); a[5] = f2bf_rne(x1.y * rn);
                a[6] = f2bf_rne(x1.z * rn); a[7] = f2bf_rne(x1.w * rn);
            }
            afrag[ct][ks] = a;
        }
    }

    const bf16x8* bsrc = (const bf16x8*)embF;   // chunk-indexed (16B units)

    // B fragments for tile t: chunks t*512 + ks*64 + lane (coalesced 1KB/inst)
    auto load_b = [&](bf16x8* bf, int t) {
        const bf16x8* p = bsrc + (size_t)t * 512 + lane;
#pragma unroll
        for (int ks = 0; ks < 8; ++ks) bf[ks] = p[ks * 64];
    };

    auto compute = [&](const bf16x8* bf, int t) {
        f32x4 a0 = {0.f, 0.f, 0.f, 0.f};
        f32x4 a1 = {0.f, 0.f, 0.f, 0.f};
        f32x4 a2 = {0.f, 0.f, 0.f, 0.f};
        f32x4 a3 = {0.f, 0.f, 0.f, 0.f};
#pragma unroll
        for (int ks = 0; ks < 8; ++ks) {
            a0 = __builtin_amdgcn_mfma_f32_16x16x32_bf16(afrag[0][ks], bf[ks], a0, 0, 0, 0);
            a1 = __builtin_amdgcn_mfma_f32_16x16x32_bf16(afrag[1][ks], bf[ks], a1, 0, 0, 0);
            a2 = __builtin_amdgcn_mfma_f32_16x16x32_bf16(afrag[2][ks], bf[ks], a2, 0, 0, 0);
            a3 = __builtin_amdgcn_mfma_f32_16x16x32_bf16(afrag[3][ks], bf[ks], a3, 0, 0, 0);
        }
        // D layout: col=lane&15=sample, row=q*4+reg=class. d = 30*log2e*cos,
        // so exp(30*cos) = exp2(d): one v_exp_f32, no mul. 4 independent
        // partial chains shorten the dependent add tail.
        float s0 = 0.f, s1 = 0.f, s2 = 0.f, s3 = 0.f;
#pragma unroll
        for (int r = 0; r < 4; ++r) {
            s0 += __builtin_amdgcn_exp2f(a0[r]);
            s1 += __builtin_amdgcn_exp2f(a1[r]);
            s2 += __builtin_amdgcn_exp2f(a2[r]);
            s3 += __builtin_amdgcn_exp2f(a3[r]);
        }
        float s = (s0 + s1) + (s2 + s3);
        s += __shfl_xor(s, 16);
        s += __shfl_xor(s, 32);
        // fire-and-forget device atomics: <=1564 adds/address over ~25us
        if (lane < 16) atomicAdd(&acc[t * 16 + cr], s);
    };

    bf16x8 b0[8], b1[8];
    load_b(b0, t0);
    for (int i = 0; i < NTW; i += 2) {
        load_b(b1, t0 + i + 1);                          // ~1 tile ahead of use
        compute(b0, t0 + i);
        load_b(b0, (i + 2) < NTW ? (t0 + i + 2) : t0);   // overrun-clamped
        compute(b1, t0 + i + 1);
    }
}

// ---- kernel 3: tiny per-sample loss finish (acc already summed) ----
__global__ __launch_bounds__(64) void k_finish(const float* __restrict__ acc,
                                               const float* __restrict__ numv,
                                               const float* __restrict__ etv,
                                               float* __restrict__ out) {
    const int b = blockIdx.x * 64 + threadIdx.x;
    const float num  = numv[b];
    const float excl = acc[b] - OOB_COLS - etv[b];   // drop padding + target col
    float term = num - logf(__expf(num) + excl + EPS_F);
#pragma unroll
    for (int o = 1; o < 64; o <<= 1) term += __shfl_xor(term, o);
    if (threadIdx.x == 0) atomicAdd(out, -term / (float)Bn);
}

extern "C" void kernel_launch(void* const* d_in, const int* in_sizes, int n_in,
                              void* d_out, int out_size, void* d_ws, size_t ws_size,
                              hipStream_t stream) {
    const float* emb = (const float*)d_in[0];   // 2048*256
    const float* W   = (const float*)d_in[1];   // 100000*256
    const int*   tgt = (const int*)d_in[2];     // 2048
    float* out = (float*)d_out;

    char* ws = (char*)d_ws;
    short* embF = (short*)ws;                       // 1 MB (fragment order)
    float* acc  = (float*)(ws + (1 << 20));         // 8 KB per-sample exp-sums
    float* numv = acc + Bn;                         // 8 KB
    float* etv  = numv + Bn;                        // 8 KB

    hipMemsetAsync(out, 0, sizeof(float), stream);
    hipMemsetAsync(acc, 0, Bn * sizeof(float), stream);
    k_prep<<<768, 256, 0, stream>>>(W, emb, tgt, embF, numv, etv);
    k_main<<<NSLICE * SSPLIT, 64, 0, stream>>>(W, embF, acc);
    k_finish<<<Bn / 64, 64, 0, stream>>>(acc, numv, etv, out);
}

// Round 2
// 258.779 us; speedup vs baseline: 1.3621x; 1.3621x over previous
//
#include <hip/hip_runtime.h>
#include <hip/hip_bf16.h>

// AngularMarginLoss: B=2048, D=256, C=100000
// loss = -mean_b( num_b - log(exp(num_b) + sum_{c!=t_b} exp(30*cos_bc) + 1e-6) )
// num_b = 30*cos(acos(clip(cos_bt)) + 0.2)
//
// Round-10: round-9 post-mortem showed the atomicAdd epilogue (3.2M contended
// atomics on 128 cache lines) serialized the per-tile tail (MfmaUtil 29->18),
// and SSPLIT=4 paid the W-normalize prologue 4x. This round keeps the extra
// waves but fixes both:
//  * 4 waves/block, one 64-col slice per block. Waves cooperatively normalize
//    W (each wave does 16 cols, 1x traffic), share bf16 A-fragments via 32KB
//    LDS, then run 32 sample-tiles each with NO further barriers (waves drift
//    -> MFMA/VALU phases stagger across the 2 co-resident blocks per SIMD).
//  * Epilogue back to round-8's coalesced 64B store into partial[sl][b];
//    k_finish does the cross-slice rowsum (stores from different waves of a
//    block hit disjoint sample ranges -> same layout works).
//  * embF stays pre-scaled by 30*log2(e): exp(30*cos) = one v_exp2_f32.

static constexpr int Bn = 2048;
static constexpr int Dn = 256;
static constexpr int Cn = 100000;
static constexpr int NSLICE = 1564;                 // 64-col slices
static constexpr int CPAD   = NSLICE * 64;          // 100096
static constexpr float OOB_COLS = (float)(CPAD - Cn);   // 96 (exp2(0)=1 each)
static constexpr int NT  = Bn / 16;                 // 128 sample tiles
static constexpr int NWV = 4;                       // waves per block
static constexpr int NTW = NT / NWV;                // 32 tiles per wave

#define SCALE_F 30.0f
#define MARGIN_F 0.2f
#define EPS_F 1e-6f
#define L2E_SCALE 43.2808512266689f   /* 30 * log2(e): exp(30*c) = 2^(L2E*c) */

typedef __attribute__((ext_vector_type(8))) short bf16x8;   // 8 bf16 = 4 VGPRs
typedef __attribute__((ext_vector_type(4))) float f32x4;

__device__ __forceinline__ short f2bf_rne(float x) {
    union { float f; unsigned int u; } v; v.f = x;
    unsigned int r = v.u + 0x7fffu + ((v.u >> 16) & 1u);
    return (short)(r >> 16);
}

// ---- kernel 1: fused prep ----
// blocks [0,256)    : pack emb fp32 -> embF (bf16, MFMA B-fragment order),
//                     PRE-SCALED by 30*log2(e) so k_main's exp is a bare v_exp.
//   chunk (t,ks,lane): embF[((t*8+ks)*64+lane)*8 .. +7] = bf16 of
//   L2E * emb[t*16 + (lane&15)][ks*32 + (lane>>4)*8 + j], j=0..7
// blocks [256,768)  : per-sample target cosine -> numv, etv (exact fp32 path)
__global__ __launch_bounds__(256) void k_prep(const float* __restrict__ W,
                                              const float* __restrict__ emb,
                                              const int* __restrict__ tgt,
                                              short* __restrict__ embF,
                                              float* __restrict__ numv,
                                              float* __restrict__ etv) {
    const int blk = blockIdx.x;
    if (blk < 256) {
        const int t     = blk >> 1;
        const int chunk = (blk & 1) * 256 + threadIdx.x;   // [0,512)
        const int ks    = chunk >> 6;
        const int lane  = chunk & 63;
        const int q     = lane >> 4;
        const int cr    = lane & 15;
        const float* src = emb + (size_t)(t * 16 + cr) * Dn + ks * 32 + q * 8;
        float4 x0 = *(const float4*)(src);
        float4 x1 = *(const float4*)(src + 4);
        bf16x8 o;
        o[0] = f2bf_rne(x0.x * L2E_SCALE); o[1] = f2bf_rne(x0.y * L2E_SCALE);
        o[2] = f2bf_rne(x0.z * L2E_SCALE); o[3] = f2bf_rne(x0.w * L2E_SCALE);
        o[4] = f2bf_rne(x1.x * L2E_SCALE); o[5] = f2bf_rne(x1.y * L2E_SCALE);
        o[6] = f2bf_rne(x1.z * L2E_SCALE); o[7] = f2bf_rne(x1.w * L2E_SCALE);
        *(bf16x8*)(embF + (size_t)((t * 8 + ks) * 64 + lane) * 8) = o;
    } else {
        const int b    = (blk - 256) * 4 + (threadIdx.x >> 6);
        const int lane = threadIdx.x & 63;
        const int t    = tgt[b];
        float4 x = *(const float4*)(W + (size_t)t * Dn + lane * 4);
        float4 e = *(const float4*)(emb + b * Dn + lane * 4);
        float dot = x.x * e.x + x.y * e.y + x.z * e.z + x.w * e.w;
        float ss  = x.x * x.x + x.y * x.y + x.z * x.z + x.w * x.w;
#pragma unroll
        for (int o = 1; o < 64; o <<= 1) {
            dot += __shfl_xor(dot, o);
            ss  += __shfl_xor(ss, o);
        }
        if (lane == 0) {
            float cosv = dot / fmaxf(sqrtf(ss), 1e-12f);
            cosv = fminf(fmaxf(cosv, -1.f), 1.f);
            const float num = SCALE_F * cosf(acosf(cosv) + MARGIN_F);
            numv[b] = num;
            etv[b]  = __expf(SCALE_F * cosv);
        }
    }
}

// ---- kernel 2: main fused GEMM + exp row-sum ----
// Block = one 64-col slice, 4 waves. Cooperative W-normalize prologue (1x
// traffic, shared via LDS), then each wave owns 32 sample-tiles, barrier-free.
__global__ __launch_bounds__(256, 2) void k_main(const float* __restrict__ W,
                                                 const short* __restrict__ embF,
                                                 float* __restrict__ partial) {
    __shared__ short afrag_sh[4 * 8 * 64 * 8];   // 32 KB, [(ct*8+ks)*64+lane]*8
    const int tid  = threadIdx.x;
    const int lane = tid & 63;
    const int wv   = tid >> 6;    // wave id 0..3 (= ct in prologue, = sample quarter)
    const int q    = lane >> 4;   // quad 0..3
    const int cr   = lane & 15;
    const int sl   = blockIdx.x;
    const int cbase = sl * 64;

    // ---- prologue: wave wv normalizes cols [cbase+wv*16, +16) ----
    // A layout (16x16x32): lane holds A[m=cr][k=q*8+j] per 32-wide k-step.
    {
        const int c = cbase + wv * 16 + cr;
        const float* wr = W + (size_t)c * Dn;
        float ss = 0.0f;
        if (c < Cn) {
#pragma unroll
            for (int ks = 0; ks < 8; ++ks) {
                float4 x0 = *(const float4*)(wr + ks * 32 + q * 8);
                float4 x1 = *(const float4*)(wr + ks * 32 + q * 8 + 4);
                ss += x0.x * x0.x + x0.y * x0.y + x0.z * x0.z + x0.w * x0.w;
                ss += x1.x * x1.x + x1.y * x1.y + x1.z * x1.z + x1.w * x1.w;
            }
        }
        // lanes {cr, cr+16, cr+32, cr+48} hold 64 distinct elements of row c
        ss += __shfl_xor(ss, 16);
        ss += __shfl_xor(ss, 32);
        const float rn = 1.0f / fmaxf(sqrtf(ss), 1e-12f);
#pragma unroll
        for (int ks = 0; ks < 8; ++ks) {
            bf16x8 a = {0, 0, 0, 0, 0, 0, 0, 0};
            if (c < Cn) {   // pass 2: reload (cache-hot), scale, convert
                float4 x0 = *(const float4*)(wr + ks * 32 + q * 8);
                float4 x1 = *(const float4*)(wr + ks * 32 + q * 8 + 4);
                a[0] = f2bf_rne(x0.x * rn); a[1] = f2bf_rne(x0.y * rn);
                a[2] = f2bf_rne(x0.z * rn); a[3] = f2bf_rne(x0.w * rn);
                a[4] = f2bf_rne(x1.x * rn); a[5] = f2bf_rne(x1.y * rn);
                a[6] = f2bf_rne(x1.z * rn); a[7] = f2bf_rne(x1.w * rn);
            }
            *(bf16x8*)(afrag_sh + (size_t)((wv * 8 + ks) * 64 + lane) * 8) = a;
        }
    }
    __syncthreads();

    // every wave pulls the full 64-col fragment set into registers
    bf16x8 afrag[4][8];
#pragma unroll
    for (int ct = 0; ct < 4; ++ct)
#pragma unroll
        for (int ks = 0; ks < 8; ++ks)
            afrag[ct][ks] = *(const bf16x8*)(afrag_sh + (size_t)((ct * 8 + ks) * 64 + lane) * 8);

    float* pout = partial + (size_t)sl * Bn;
    const bf16x8* bsrc = (const bf16x8*)embF;   // chunk-indexed (16B units)
    const int t0 = wv * NTW;                    // this wave's sample quarter

    // B fragments for tile t: chunks t*512 + ks*64 + lane (coalesced 1KB/inst)
    auto load_b = [&](bf16x8* bf, int t) {
        const bf16x8* p = bsrc + (size_t)t * 512 + lane;
#pragma unroll
        for (int ks = 0; ks < 8; ++ks) bf[ks] = p[ks * 64];
    };

    auto compute = [&](const bf16x8* bf, int t) {
        f32x4 a0 = {0.f, 0.f, 0.f, 0.f};
        f32x4 a1 = {0.f, 0.f, 0.f, 0.f};
        f32x4 a2 = {0.f, 0.f, 0.f, 0.f};
        f32x4 a3 = {0.f, 0.f, 0.f, 0.f};
#pragma unroll
        for (int ks = 0; ks < 8; ++ks) {
            a0 = __builtin_amdgcn_mfma_f32_16x16x32_bf16(afrag[0][ks], bf[ks], a0, 0, 0, 0);
            a1 = __builtin_amdgcn_mfma_f32_16x16x32_bf16(afrag[1][ks], bf[ks], a1, 0, 0, 0);
            a2 = __builtin_amdgcn_mfma_f32_16x16x32_bf16(afrag[2][ks], bf[ks], a2, 0, 0, 0);
            a3 = __builtin_amdgcn_mfma_f32_16x16x32_bf16(afrag[3][ks], bf[ks], a3, 0, 0, 0);
        }
        // D layout: col=lane&15=sample, row=q*4+reg=class. d = 30*log2e*cos,
        // so exp(30*cos) = exp2(d): one v_exp_f32, no mul. 4 independent
        // partial chains shorten the dependent add tail.
        float s0 = 0.f, s1 = 0.f, s2 = 0.f, s3 = 0.f;
#pragma unroll
        for (int r = 0; r < 4; ++r) {
            s0 += __builtin_amdgcn_exp2f(a0[r]);
            s1 += __builtin_amdgcn_exp2f(a1[r]);
            s2 += __builtin_amdgcn_exp2f(a2[r]);
            s3 += __builtin_amdgcn_exp2f(a3[r]);
        }
        float s = (s0 + s1) + (s2 + s3);
        s += __shfl_xor(s, 16);
        s += __shfl_xor(s, 32);
        if (lane < 16) pout[t * 16 + cr] = s;   // coalesced 64B store
    };

    bf16x8 b0[8], b1[8];
    load_b(b0, t0);
    for (int i = 0; i < NTW; i += 2) {
        load_b(b1, t0 + i + 1);                          // ~1 tile ahead of use
        compute(b0, t0 + i);
        load_b(b0, (i + 2) < NTW ? (t0 + i + 2) : t0);   // overrun-clamped
        compute(b1, t0 + i + 1);
    }
}

// ---- kernel 3: fused rowsum + loss ----
// 32 blocks x 256 thr; block owns 64 samples; tid = qq*64 + l, qq = slice quarter.
__global__ __launch_bounds__(256) void k_finish(const float* __restrict__ partial,
                                                const float* __restrict__ numv,
                                                const float* __restrict__ etv,
                                                float* __restrict__ out) {
    __shared__ float red[64];
    const int l  = threadIdx.x & 63;
    const int qq = threadIdx.x >> 6;
    const int b  = blockIdx.x * 64 + l;

    if (threadIdx.x < 64) red[threadIdx.x] = 0.0f;
    __syncthreads();

    const int s0 = qq * (NSLICE / 4);            // 1564 = 4*391 exact
    const int s1 = s0 + (NSLICE / 4);
    float acc = 0.0f;
    for (int s = s0; s < s1; ++s) acc += partial[(size_t)s * Bn + b];
    atomicAdd(&red[l], acc);
    __syncthreads();

    if (threadIdx.x < 64) {
        const float num  = numv[b];
        const float excl = red[l] - OOB_COLS - etv[b];   // drop padding + target col
        const float denom = __expf(num) + excl;
        float term = num - logf(denom + EPS_F);
#pragma unroll
        for (int o = 1; o < 64; o <<= 1) term += __shfl_xor(term, o);
        if (l == 0) atomicAdd(out, -term / (float)Bn);
    }
}

extern "C" void kernel_launch(void* const* d_in, const int* in_sizes, int n_in,
                              void* d_out, int out_size, void* d_ws, size_t ws_size,
                              hipStream_t stream) {
    const float* emb = (const float*)d_in[0];   // 2048*256
    const float* W   = (const float*)d_in[1];   // 100000*256
    const int*   tgt = (const int*)d_in[2];     // 2048
    float* out = (float*)d_out;

    char* ws = (char*)d_ws;
    short* embF    = (short*)ws;                             // 1 MB (fragment order)
    float* partial = (float*)(ws + (1 << 20));               // 1564*2048*4 = 12.8 MB
    float* numv    = partial + (size_t)NSLICE * Bn;          // 8 KB
    float* etv     = numv + Bn;                              // 8 KB

    hipMemsetAsync(out, 0, sizeof(float), stream);
    k_prep<<<768, 256, 0, stream>>>(W, emb, tgt, embF, numv, etv);
    k_main<<<NSLICE, 256, 0, stream>>>(W, embF, partial);
    k_finish<<<32, 256, 0, stream>>>(partial, numv, etv, out);
}